// Round 5
// baseline (951.847 us; speedup 1.0000x reference)
//
#include <hip/hip_runtime.h>
#include <math.h>

typedef unsigned short u16;
typedef __bf16 bf16x8 __attribute__((ext_vector_type(8)));
typedef float floatx4 __attribute__((ext_vector_type(4)));

constexpr int N_TOK = 8192;
constexpr int DIM   = 1024;
// softmax in exp2 domain: s2 = dot * (1/sqrt(1024)) * log2(e)
constexpr float SC2 = 0.03125f * 1.4426950408889634f;

__device__ __forceinline__ u16 f2bf(float f) {
  unsigned u = __builtin_bit_cast(unsigned, f);
  unsigned r = u + 0x7fffu + ((u >> 16) & 1u);  // round-to-nearest-even
  return (u16)(r >> 16);
}
__device__ __forceinline__ float bf2f(u16 h) {
  unsigned u = ((unsigned)h) << 16;
  return __builtin_bit_cast(float, u);
}
__device__ __forceinline__ floatx4 mfma16(bf16x8 a, bf16x8 b, floatx4 c) {
  return __builtin_amdgcn_mfma_f32_16x16x32_bf16(a, b, c, 0, 0, 0);
}
// async global->LDS, 16B per lane; LDS side is wave-uniform base + lane*16.
__device__ __forceinline__ void gload_lds16(const void* g, void* l) {
  using GP = const unsigned __attribute__((address_space(1)))*;
  using LP = unsigned __attribute__((address_space(3)))*;
  __builtin_amdgcn_global_load_lds((GP)(uintptr_t)g, (LP)(uintptr_t)l, 16, 0, 0);
}

// ---------------- X -> Xhi/Xlo (row-major) + Xt (bf16 hi, [DIM][N_TOK]) ----
__global__ __launch_bounds__(256, 4) void split_x(const float* __restrict__ X,
                                                  u16* __restrict__ Xhi,
                                                  u16* __restrict__ Xlo,
                                                  u16* __restrict__ Xt) {
  __shared__ u16 T[64][72];
  const int tok0 = blockIdx.x * 64, d0 = blockIdx.y * 64;
  const int t = threadIdx.x;
  {
    const int tok = t >> 2, dc = (t & 3) * 16;
    const float* src = X + (size_t)(tok0 + tok) * DIM + d0 + dc;
    u16 h[16], lo[16];
#pragma unroll
    for (int c = 0; c < 16; c += 4) {
      float4 v = *(const float4*)(src + c);
      float vv[4] = {v.x, v.y, v.z, v.w};
#pragma unroll
      for (int q = 0; q < 4; ++q) {
        h[c + q] = f2bf(vv[q]);
        lo[c + q] = f2bf(vv[q] - bf2f(h[c + q]));
        T[dc + c + q][tok] = h[c + q];
      }
    }
    uint4 hv, lv;
    unsigned* hp = (unsigned*)&hv; unsigned* lp = (unsigned*)&lv;
#pragma unroll
    for (int q = 0; q < 4; ++q) {
      hp[q] = (unsigned)h[q * 2] | ((unsigned)h[q * 2 + 1] << 16);
      lp[q] = (unsigned)lo[q * 2] | ((unsigned)lo[q * 2 + 1] << 16);
    }
    size_t off = (size_t)(tok0 + tok) * DIM + d0 + dc;
    *(uint4*)(Xhi + off) = hv;
    *(uint4*)(Xlo + off) = lv;
#pragma unroll
    for (int q = 0; q < 4; ++q) {
      hp[q] = (unsigned)h[8 + q * 2] | ((unsigned)h[8 + q * 2 + 1] << 16);
      lp[q] = (unsigned)lo[8 + q * 2] | ((unsigned)lo[8 + q * 2 + 1] << 16);
    }
    *(uint4*)(Xhi + off + 8) = hv;
    *(uint4*)(Xlo + off + 8) = lv;
  }
  __syncthreads();
  {
    const int d = t >> 3, tk = (t & 7) * 8;
#pragma unroll
    for (int rep = 0; rep < 2; ++rep) {
      int dd = d + rep * 32;
      *(uint4*)(Xt + (size_t)(d0 + dd) * N_TOK + tok0 + tk) = *(uint4*)&T[dd][tk];
    }
  }
}

// ---------------- W[k][n] -> Wt_hi/Wt_lo [n][k] (bf16 split) --------------
__global__ __launch_bounds__(256, 4) void split_wt(const float* __restrict__ W0,
                                                   const float* __restrict__ W1,
                                                   u16* __restrict__ Whi,
                                                   u16* __restrict__ Wlo) {
  __shared__ float Tf[64][65];
  const int k0 = blockIdx.x * 64, n0 = blockIdx.y * 64;
  const int sel = blockIdx.z;
  const float* W = sel ? W1 : W0;
  u16* Oh = Whi + (size_t)sel * DIM * DIM;
  u16* Ol = Wlo + (size_t)sel * DIM * DIM;
  const int t = threadIdx.x;
  {
    const int k = t >> 2, nc = (t & 3) * 16;
    const float* src = W + (size_t)(k0 + k) * DIM + n0 + nc;
#pragma unroll
    for (int c = 0; c < 16; c += 4) {
      float4 v = *(const float4*)(src + c);
      Tf[nc + c + 0][k] = v.x;
      Tf[nc + c + 1][k] = v.y;
      Tf[nc + c + 2][k] = v.z;
      Tf[nc + c + 3][k] = v.w;
    }
  }
  __syncthreads();
  {
    const int n = t >> 3, kk = (t & 7) * 8;
#pragma unroll
    for (int rep = 0; rep < 2; ++rep) {
      int nn = n + rep * 32;
      uint4 hv, lv;
      unsigned* hp = (unsigned*)&hv; unsigned* lp = (unsigned*)&lv;
#pragma unroll
      for (int q = 0; q < 4; ++q) {
        u16 h0, l0, h1, l1;
        float a = Tf[nn][kk + q * 2], b = Tf[nn][kk + q * 2 + 1];
        h0 = f2bf(a); l0 = f2bf(a - bf2f(h0));
        h1 = f2bf(b); l1 = f2bf(b - bf2f(h1));
        hp[q] = (unsigned)h0 | ((unsigned)h1 << 16);
        lp[q] = (unsigned)l0 | ((unsigned)l1 << 16);
      }
      size_t off = (size_t)(n0 + nn) * DIM + k0 + kk;
      *(uint4*)(Oh + off) = hv;
      *(uint4*)(Ol + off) = lv;
    }
  }
}

// ---------------- Fused projections: {Q,K} = X @ {Wq,Wk}, split-3 MFMA ----
// Block 256 rows x 128 cols; 4 waves of 128x64. grid (16, 32).
__global__ __launch_bounds__(256, 2) void gemm_proj(const u16* __restrict__ Xhi,
                                                    const u16* __restrict__ Xlo,
                                                    const u16* __restrict__ Wthi,
                                                    const u16* __restrict__ Wtlo,
                                                    u16* __restrict__ Qhi,
                                                    u16* __restrict__ Qlo,
                                                    u16* __restrict__ Khi,
                                                    u16* __restrict__ Klo) {
  // Ahi[0..15] Alo[16..31] Bhi[32..39] Blo[40..47], each chunk 512 elems
  __shared__ u16 T[48 * 512];
  const int t = threadIdx.x, w = t >> 6, l = t & 63;
  const int l15 = l & 15, l4 = l >> 4;
  const int nb = blockIdx.x, rb = blockIdx.y;
  const int sel = nb >> 3, col0 = (nb & 7) * 128;
  const int wm = w & 1, wn = w >> 1;
  const int lrow = l >> 2, lk = (l & 3) * 8;

  const u16* Arow = Xhi + (size_t)rb * 256 * DIM;  // Alo = Arow + MATOFF
  const size_t ALO = (size_t)(Xlo - Xhi);
  const u16* Brow = Wthi + (size_t)sel * DIM * DIM + (size_t)col0 * DIM;
  const size_t BLO = (size_t)(Wtlo - Wthi);

  floatx4 acc[8][4] = {};

  for (int k0 = 0; k0 < DIM; k0 += 32) {
    __syncthreads();
#pragma unroll
    for (int n = 0; n < 12; ++n) {
      int c = w * 12 + n;
      const u16* src;
      if (c < 16)      src = Arow + (size_t)(c * 16 + lrow) * DIM;
      else if (c < 32) src = Arow + ALO + (size_t)((c - 16) * 16 + lrow) * DIM;
      else if (c < 40) src = Brow + (size_t)((c - 32) * 16 + lrow) * DIM;
      else             src = Brow + BLO + (size_t)((c - 40) * 16 + lrow) * DIM;
      gload_lds16(src + k0 + lk, &T[c * 512]);
    }
    __syncthreads();
    bf16x8 bH[4], bL[4];
#pragma unroll
    for (int j = 0; j < 4; ++j) {
      int br = wn * 64 + j * 16 + l15;
      bH[j] = *(const bf16x8*)&T[16384 + br * 32 + l4 * 8];
      bL[j] = *(const bf16x8*)&T[20480 + br * 32 + l4 * 8];
    }
#pragma unroll
    for (int i = 0; i < 8; ++i) {
      int ar = wm * 128 + i * 16 + l15;
      bf16x8 aH = *(const bf16x8*)&T[ar * 32 + l4 * 8];
      bf16x8 aL = *(const bf16x8*)&T[8192 + ar * 32 + l4 * 8];
#pragma unroll
      for (int j = 0; j < 4; ++j) {
        acc[i][j] = mfma16(aL, bH[j], acc[i][j]);
        acc[i][j] = mfma16(aH, bL[j], acc[i][j]);
        acc[i][j] = mfma16(aH, bH[j], acc[i][j]);
      }
    }
  }

  u16* Oh = sel ? Khi : Qhi;
  u16* Ol = sel ? Klo : Qlo;
#pragma unroll
  for (int i = 0; i < 8; ++i)
#pragma unroll
    for (int r = 0; r < 4; ++r) {
      size_t R = (size_t)(rb * 256 + wm * 128 + i * 16 + l4 * 4 + r);
#pragma unroll
      for (int j = 0; j < 4; ++j) {
        float v = acc[i][j][r];
        u16 h = f2bf(v);
        u16 lo = f2bf(v - bf2f(h));
        size_t off = R * DIM + (col0 + wn * 64 + j * 16 + l15);
        Oh[off] = h;
        Ol[off] = lo;
      }
    }
}

// ---------------- Pass S: P' = exp2(QK^T*SC2 - mb), Mpart, Lpart ---------
// Block 256 q-rows x 128 k-tokens; 4 waves of 128x64. grid (64, 32).
__global__ __launch_bounds__(256, 2) void gemm_s(const u16* __restrict__ Qhi,
                                                 const u16* __restrict__ Qlo,
                                                 const u16* __restrict__ Khi,
                                                 const u16* __restrict__ Klo,
                                                 u16* __restrict__ P,
                                                 float* __restrict__ Mpart,
                                                 float* __restrict__ Lpart) {
  __shared__ u16 T[48 * 512];
  __shared__ float Mw[2][256], Lw[2][256];
  const int t = threadIdx.x, w = t >> 6, l = t & 63;
  const int l15 = l & 15, l4 = l >> 4;
  const int cb = blockIdx.x, rb = blockIdx.y;
  const int wm = w & 1, wn = w >> 1;
  const int lrow = l >> 2, lk = (l & 3) * 8;

  const u16* Arow = Qhi + (size_t)rb * 256 * DIM;
  const size_t ALO = (size_t)(Qlo - Qhi);
  const u16* Brow = Khi + (size_t)cb * 128 * DIM;
  const size_t BLO = (size_t)(Klo - Khi);

  floatx4 acc[8][4] = {};

  for (int k0 = 0; k0 < DIM; k0 += 32) {
    __syncthreads();
#pragma unroll
    for (int n = 0; n < 12; ++n) {
      int c = w * 12 + n;
      const u16* src;
      if (c < 16)      src = Arow + (size_t)(c * 16 + lrow) * DIM;
      else if (c < 32) src = Arow + ALO + (size_t)((c - 16) * 16 + lrow) * DIM;
      else if (c < 40) src = Brow + (size_t)((c - 32) * 16 + lrow) * DIM;
      else             src = Brow + BLO + (size_t)((c - 40) * 16 + lrow) * DIM;
      gload_lds16(src + k0 + lk, &T[c * 512]);
    }
    __syncthreads();
    bf16x8 bH[4], bL[4];
#pragma unroll
    for (int j = 0; j < 4; ++j) {
      int br = wn * 64 + j * 16 + l15;
      bH[j] = *(const bf16x8*)&T[16384 + br * 32 + l4 * 8];
      bL[j] = *(const bf16x8*)&T[20480 + br * 32 + l4 * 8];
    }
#pragma unroll
    for (int i = 0; i < 8; ++i) {
      int ar = wm * 128 + i * 16 + l15;
      bf16x8 aH = *(const bf16x8*)&T[ar * 32 + l4 * 8];
      bf16x8 aL = *(const bf16x8*)&T[8192 + ar * 32 + l4 * 8];
#pragma unroll
      for (int j = 0; j < 4; ++j) {
        acc[i][j] = mfma16(aL, bH[j], acc[i][j]);
        acc[i][j] = mfma16(aH, bL[j], acc[i][j]);
        acc[i][j] = mfma16(aH, bH[j], acc[i][j]);
      }
    }
  }

  // ---- epilogue ----
#pragma unroll
  for (int i = 0; i < 8; ++i)
#pragma unroll
    for (int j = 0; j < 4; ++j)
#pragma unroll
      for (int r = 0; r < 4; ++r) acc[i][j][r] *= SC2;

#pragma unroll
  for (int i = 0; i < 8; ++i)
#pragma unroll
    for (int r = 0; r < 4; ++r) {
      float m = fmaxf(fmaxf(acc[i][0][r], acc[i][1][r]),
                      fmaxf(acc[i][2][r], acc[i][3][r]));
#pragma unroll
      for (int off = 1; off <= 8; off <<= 1) m = fmaxf(m, __shfl_xor(m, off, 64));
      if (l15 == 0) Mw[wn][wm * 128 + i * 16 + l4 * 4 + r] = m;
    }
  __syncthreads();
#pragma unroll
  for (int i = 0; i < 8; ++i)
#pragma unroll
    for (int r = 0; r < 4; ++r) {
      int lr = wm * 128 + i * 16 + l4 * 4 + r;
      float mb = fmaxf(Mw[0][lr], Mw[1][lr]);
      float ls = 0.f;
      size_t R = (size_t)(rb * 256 + lr);
#pragma unroll
      for (int j = 0; j < 4; ++j) {
        float pv = __builtin_amdgcn_exp2f(acc[i][j][r] - mb);
        u16 h = f2bf(pv);
        ls += bf2f(h);
        __builtin_nontemporal_store(h, &P[R * N_TOK + (cb * 128 + wn * 64 + j * 16 + l15)]);
      }
#pragma unroll
      for (int off = 1; off <= 8; off <<= 1) ls += __shfl_xor(ls, off, 64);
      if (l15 == 0) Lw[wn][lr] = ls;
    }
  __syncthreads();
  {
    Mpart[(size_t)cb * N_TOK + rb * 256 + t] = fmaxf(Mw[0][t], Mw[1][t]);
    Lpart[(size_t)cb * N_TOK + rb * 256 + t] = Lw[0][t] + Lw[1][t];
  }
}

// ---------------- row stats: m, 1/l ----------------
__global__ __launch_bounds__(256, 4) void rowstats(const float* __restrict__ Mpart,
                                                   const float* __restrict__ Lpart,
                                                   float* __restrict__ m_row,
                                                   float* __restrict__ linv) {
  const int r = blockIdx.x * 256 + threadIdx.x;
  float m = -INFINITY;
#pragma unroll 8
  for (int tb = 0; tb < 64; ++tb) m = fmaxf(m, Mpart[(size_t)tb * N_TOK + r]);
  float l = 0.f;
#pragma unroll 8
  for (int tb = 0; tb < 64; ++tb)
    l += __builtin_amdgcn_exp2f(Mpart[(size_t)tb * N_TOK + r] - m) *
         Lpart[(size_t)tb * N_TOK + r];
  m_row[r] = m;
  linv[r] = 1.0f / l;
}

// ---------------- scale P' by exp2(mb - m), in place ----------------
__global__ __launch_bounds__(256, 4) void scale_p(u16* __restrict__ P,
                                                  const float* __restrict__ Mpart,
                                                  const float* __restrict__ m_row) {
  const int r = blockIdx.x;
  const int j = threadIdx.x;
  const float m = m_row[r];
  const float f = __builtin_amdgcn_exp2f(Mpart[(size_t)(j >> 2) * N_TOK + r] - m);
  u16* p = P + (size_t)r * N_TOK + j * 32;
#pragma unroll
  for (int c = 0; c < 4; ++c) {
    uint4 v = *(uint4*)(p + c * 8);
    unsigned vv[4] = {v.x, v.y, v.z, v.w};
#pragma unroll
    for (int q = 0; q < 4; ++q) {
      u16 lo = (u16)(vv[q] & 0xffffu), hi = (u16)(vv[q] >> 16);
      lo = f2bf(bf2f(lo) * f);
      hi = f2bf(bf2f(hi) * f);
      vv[q] = (unsigned)lo | ((unsigned)hi << 16);
    }
    v.x = vv[0]; v.y = vv[1]; v.z = vv[2]; v.w = vv[3];
    *(uint4*)(p + c * 8) = v;
  }
}

// ---------------- Pass O: Out = (P' @ Xt^T) * linv ----------------
// Block 256 rows x 128 cols; 4 waves of 128x64. grid (8, 32).
__global__ __launch_bounds__(256, 2) void gemm_o(const u16* __restrict__ P,
                                                 const u16* __restrict__ Xt,
                                                 const float* __restrict__ linv,
                                                 float* __restrict__ Out) {
  // A[0..15] (P rows, single bf16), B[16..23] (Xt rows)
  __shared__ u16 T[24 * 512];
  const int t = threadIdx.x, w = t >> 6, l = t & 63;
  const int l15 = l & 15, l4 = l >> 4;
  const int nb = blockIdx.x, rb = blockIdx.y;
  const int wm = w & 1, wn = w >> 1;
  const int lrow = l >> 2, lk = (l & 3) * 8;

  const u16* Arow = P + (size_t)rb * 256 * N_TOK;
  const u16* Brow = Xt + (size_t)nb * 128 * N_TOK;

  floatx4 acc[8][4] = {};

  for (int k0 = 0; k0 < N_TOK; k0 += 32) {
    __syncthreads();
#pragma unroll
    for (int n = 0; n < 6; ++n) {
      int c = w * 6 + n;
      const u16* src;
      if (c < 16) src = Arow + (size_t)(c * 16 + lrow) * N_TOK;
      else        src = Brow + (size_t)((c - 16) * 16 + lrow) * N_TOK;
      gload_lds16(src + k0 + lk, &T[c * 512]);
    }
    __syncthreads();
    bf16x8 bfr[4];
#pragma unroll
    for (int j = 0; j < 4; ++j)
      bfr[j] = *(const bf16x8*)&T[8192 + (wn * 64 + j * 16 + l15) * 32 + l4 * 8];
#pragma unroll
    for (int i = 0; i < 8; ++i) {
      bf16x8 af = *(const bf16x8*)&T[(wm * 128 + i * 16 + l15) * 32 + l4 * 8];
#pragma unroll
      for (int j = 0; j < 4; ++j) acc[i][j] = mfma16(af, bfr[j], acc[i][j]);
    }
  }

#pragma unroll
  for (int i = 0; i < 8; ++i)
#pragma unroll
    for (int r = 0; r < 4; ++r) {
      int R = rb * 256 + wm * 128 + i * 16 + l4 * 4 + r;
      float inv = linv[R];
      float* orow = Out + (size_t)R * DIM + nb * 128 + wn * 64 + l15;
#pragma unroll
      for (int j = 0; j < 4; ++j) orow[j * 16] = acc[i][j][r] * inv;
    }
}

extern "C" void kernel_launch(void* const* d_in, const int* in_sizes, int n_in,
                              void* d_out, int out_size, void* d_ws, size_t ws_size,
                              hipStream_t stream) {
  const float* Wq = (const float*)d_in[0];
  const float* Wk = (const float*)d_in[1];
  const float* X  = (const float*)d_in[2];
  float* Out = (float*)d_out;

  constexpr size_t MAT = (size_t)N_TOK * DIM;   // 8 Mi elems
  constexpr size_t WMAT = (size_t)DIM * DIM;    // 1 Mi elems
  u16* Qhi = (u16*)d_ws;
  u16* Qlo = Qhi + MAT;
  u16* Khi = Qlo + MAT;
  u16* Klo = Khi + MAT;
  u16* Xt  = Klo + MAT;
  u16* Xhi = Xt + MAT;
  u16* Xlo = Xhi + MAT;
  u16* Wthi = Xlo + MAT;          // [2][1024][1024]
  u16* Wtlo = Wthi + 2 * WMAT;
  u16* P   = Wtlo + 2 * WMAT;     // 8192x8192 bf16 = 128 MB
  float* Mpart = (float*)(P + (size_t)N_TOK * N_TOK);
  float* Lpart = Mpart + (size_t)64 * N_TOK;
  float* m_row = Lpart + (size_t)64 * N_TOK;
  float* linv  = m_row + N_TOK;

  split_x<<<dim3(N_TOK / 64, DIM / 64), 256, 0, stream>>>(X, Xhi, Xlo, Xt);
  split_wt<<<dim3(DIM / 64, DIM / 64, 2), 256, 0, stream>>>(Wq, Wk, Wthi, Wtlo);
  gemm_proj<<<dim3(16, 32), 256, 0, stream>>>(Xhi, Xlo, Wthi, Wtlo,
                                              Qhi, Qlo, Khi, Klo);
  gemm_s<<<dim3(64, 32), 256, 0, stream>>>(Qhi, Qlo, Khi, Klo, P, Mpart, Lpart);
  rowstats<<<dim3(32), 256, 0, stream>>>(Mpart, Lpart, m_row, linv);
  scale_p<<<dim3(N_TOK), 256, 0, stream>>>(P, Mpart, m_row);
  gemm_o<<<dim3(8, 32), 256, 0, stream>>>(P, Xt, linv, Out);
}